// Round 1
// baseline (358.488 us; speedup 1.0000x reference)
//
#include <hip/hip_runtime.h>
#include <hip/hip_bf16.h>

// Problem constants
#define BB 2
#define TT 2048
#define CC 768
#define HH 12
#define DD 64
#define NQKV 2304           // 3*H*D
#define MTOT (BB*TT)        // 4096

typedef __bf16 bf16x8 __attribute__((ext_vector_type(8)));
typedef __bf16 bf16x4 __attribute__((ext_vector_type(4)));
typedef float  f32x4  __attribute__((ext_vector_type(4)));

__device__ __forceinline__ f32x4 mfma16(bf16x8 a, bf16x8 b, f32x4 c) {
    return __builtin_amdgcn_mfma_f32_16x16x32_bf16(a, b, c, 0, 0, 0);
}

// ---------------------------------------------------------------------------
// 1) f32 -> bf16 convert for x, w_attn, w_proj (one fused elementwise kernel)
// ---------------------------------------------------------------------------
__global__ __launch_bounds__(256) void cvt_bf16_kernel(
    const float* __restrict__ x, const float* __restrict__ wa, const float* __restrict__ wp,
    __bf16* __restrict__ xb, __bf16* __restrict__ wab, __bf16* __restrict__ wpb)
{
    const long NX = (long)MTOT * CC;       // 3,145,728
    const long NWA = (long)NQKV * CC;      // 1,769,472
    const long NWP = (long)CC * (HH*DD);   // 589,824
    long idx = ((long)blockIdx.x * 256 + threadIdx.x) * 4;
    const float* src; __bf16* dst; long off;
    if (idx < NX)            { src = x;  dst = xb;  off = idx; }
    else if (idx < NX + NWA) { src = wa; dst = wab; off = idx - NX; }
    else                     { src = wp; dst = wpb; off = idx - NX - NWA; }
    float4 v = *(const float4*)(src + off);
    bf16x4 o;
    o[0] = (__bf16)v.x; o[1] = (__bf16)v.y; o[2] = (__bf16)v.z; o[3] = (__bf16)v.w;
    *(bf16x4*)(dst + off) = o;
}

// ---------------------------------------------------------------------------
// 2) NT GEMM (A[M,K] row-major, B[N,K] row-major), 128x128 tile, BK=32,
//    bf16 MFMA 16x16x32. EPI=0: QKV epilogue (scatter to q,k,vT bf16).
//    EPI=1: proj epilogue (f32 out).
// ---------------------------------------------------------------------------
template<int EPI>
__global__ __launch_bounds__(256, 2) void gemm_nt_kernel(
    const __bf16* __restrict__ A, const __bf16* __restrict__ Bw,
    const float* __restrict__ bias,
    __bf16* __restrict__ oQ, __bf16* __restrict__ oK, __bf16* __restrict__ oVT,
    float* __restrict__ oOut, int K)
{
    __shared__ __align__(16) __bf16 As[128 * 32];
    __shared__ __align__(16) __bf16 Bs[128 * 32];
    const int tid = threadIdx.x;
    const int m0 = blockIdx.y * 128, n0 = blockIdx.x * 128;
    const int w = tid >> 6, lane = tid & 63, quad = lane >> 4, l16 = lane & 15;
    const int wm = (w >> 1) * 64, wn = (w & 1) * 64;
    const int sr = tid >> 2, scc = (tid & 3) * 8;   // staging row / col

    f32x4 acc[4][4] = {};

    for (int kt = 0; kt < K; kt += 32) {
        __syncthreads();
        *(uint4*)(As + sr * 32 + scc)        = *(const uint4*)(A  + (long)(m0 + sr) * K      + kt + scc);
        *(uint4*)(As + (sr + 64) * 32 + scc) = *(const uint4*)(A  + (long)(m0 + sr + 64) * K + kt + scc);
        *(uint4*)(Bs + sr * 32 + scc)        = *(const uint4*)(Bw + (long)(n0 + sr) * K      + kt + scc);
        *(uint4*)(Bs + (sr + 64) * 32 + scc) = *(const uint4*)(Bw + (long)(n0 + sr + 64) * K + kt + scc);
        __syncthreads();

        bf16x8 af[4], bfr[4];
#pragma unroll
        for (int g = 0; g < 4; g++)  af[g]  = *(const bf16x8*)(As + (wm + g * 16 + l16) * 32 + quad * 8);
#pragma unroll
        for (int jb = 0; jb < 4; jb++) bfr[jb] = *(const bf16x8*)(Bs + (wn + jb * 16 + l16) * 32 + quad * 8);
#pragma unroll
        for (int g = 0; g < 4; g++)
#pragma unroll
            for (int jb = 0; jb < 4; jb++)
                acc[g][jb] = mfma16(af[g], bfr[jb], acc[g][jb]);
    }

    // epilogue: C/D layout col = lane&15, row = quad*4 + reg
#pragma unroll
    for (int jb = 0; jb < 4; jb++) {
        const int n = n0 + wn + jb * 16 + l16;
        const float bv = bias[n];
#pragma unroll
        for (int g = 0; g < 4; g++) {
#pragma unroll
            for (int r = 0; r < 4; r++) {
                const int m = m0 + wm + g * 16 + quad * 4 + r;
                const float v = acc[g][jb][r] + bv;
                if (EPI == 0) {
                    const int which = n / 768;
                    const int rem = n - which * 768;
                    const int h = rem >> 6, d = rem & 63;
                    const int b = m >> 11, t = m & 2047;
                    const __bf16 hv = (__bf16)v;
                    if (which == 0)      oQ [(((b * HH + h) * TT + t) << 6) + d] = hv;
                    else if (which == 1) oK [(((b * HH + h) * TT + t) << 6) + d] = hv;
                    else                 oVT[((((b * HH + h) << 6) + d) * TT) + t] = hv;
                } else {
                    oOut[(long)m * CC + n] = v;
                }
            }
        }
    }
}

// ---------------------------------------------------------------------------
// 3) Head-0 selection scores: S[b,i,j] = (1<=j<i) ? relu(q0_i . k0_j * 0.125) : 0
//    Only lower-triangular 64x64 tiles launched (others exit).
// ---------------------------------------------------------------------------
__global__ __launch_bounds__(256) void sgemm_kernel(
    const __bf16* __restrict__ q, const __bf16* __restrict__ k, float* __restrict__ S)
{
    const int tj = blockIdx.x, ti = blockIdx.y, b = blockIdx.z;
    if (tj > ti) return;
    const int w = threadIdx.x >> 6, lane = threadIdx.x & 63, quad = lane >> 4, l16 = lane & 15;
    const int i0 = ti * 64 + w * 16;

    const __bf16* qp = q + (((long)(b * HH + 0) * TT + i0 + l16) << 6) + quad * 8;
    bf16x8 a0 = *(const bf16x8*)qp, a1 = *(const bf16x8*)(qp + 32);
    const __bf16* kbase = k + ((long)(b * HH + 0) * TT << 6);

#pragma unroll
    for (int jb = 0; jb < 4; jb++) {
        const __bf16* kp = kbase + (((long)(tj * 64 + jb * 16 + l16)) << 6) + quad * 8;
        bf16x8 b0 = *(const bf16x8*)kp, b1 = *(const bf16x8*)(kp + 32);
        f32x4 acc = {};
        acc = mfma16(a0, b0, acc);
        acc = mfma16(a1, b1, acc);
        const int j = tj * 64 + jb * 16 + l16;
#pragma unroll
        for (int r = 0; r < 4; r++) {
            const int i = i0 + quad * 4 + r;
            float v = fmaxf(acc[r] * 0.125f, 0.0f);
            v = (j >= 1 && j < i) ? v : 0.0f;
            S[((long)b * TT + i) * TT + j] = v;
        }
    }
}

// ---------------------------------------------------------------------------
// 4) Exclusive cumsum over query dim (axis i), per column j: 2-pass chunked.
//    chunk = 128 rows, 16 chunks. Pass A: chunk sums. Pass C: in-place scan.
// ---------------------------------------------------------------------------
__global__ __launch_bounds__(256) void scan_sum_kernel(
    const float* __restrict__ S, float* __restrict__ csum)
{
    const int j = blockIdx.x * 256 + threadIdx.x;
    const int chunk = blockIdx.y, b = blockIdx.z;
    const int ib = chunk * 128;
    const float* p = S + ((long)b * TT + ib) * TT + j;
    float s = 0.0f;
#pragma unroll 4
    for (int ii = 0; ii < 128; ii++) {
        float v = p[(long)ii * TT];
        s += ((ib + ii) > j) ? v : 0.0f;
    }
    csum[(b * 16 + chunk) * TT + j] = s;
}

__global__ __launch_bounds__(256) void scan_write_kernel(
    float* __restrict__ S, const float* __restrict__ csum)
{
    const int j = blockIdx.x * 256 + threadIdx.x;
    const int chunk = blockIdx.y, b = blockIdx.z;
    const int ib = chunk * 128;
    float off = 0.0f;
    for (int c = 0; c < chunk; c++) off += csum[(b * 16 + c) * TT + j];
    float* p = S + ((long)b * TT + ib) * TT + j;
#pragma unroll 4
    for (int ii = 0; ii < 128; ii++) {
        float v = p[(long)ii * TT];
        v = ((ib + ii) > j) ? v : 0.0f;
        p[(long)ii * TT] = off;    // exclusive: write before add
        off += v;
    }
}

// ---------------------------------------------------------------------------
// 5) Flash attention with F subtraction. Block = 4 independent waves, each
//    owns 16 q-rows. K-tiles of 32. P transposed via wave-private LDS.
// ---------------------------------------------------------------------------
__global__ __launch_bounds__(256, 2) void flash_kernel(
    const __bf16* __restrict__ q, const __bf16* __restrict__ k, const __bf16* __restrict__ vT,
    const float* __restrict__ F, __bf16* __restrict__ y)
{
    __shared__ __align__(16) __bf16 Pls[4][16 * 40];   // per-wave 16x32 P tile, stride 40
    const int qt = blockIdx.x, h = blockIdx.y, b = blockIdx.z;
    const int w = threadIdx.x >> 6, lane = threadIdx.x & 63, quad = lane >> 4, l16 = lane & 15;
    const int i0 = qt * 64 + w * 16;
    const int jmax = i0 + 15;

    const __bf16* qp = q + (((long)(b * HH + h) * TT + i0 + l16) << 6) + quad * 8;
    const bf16x8 aq0 = *(const bf16x8*)qp;
    const bf16x8 aq1 = *(const bf16x8*)(qp + 32);
    const __bf16* kb = k  + ((long)(b * HH + h) * TT << 6);
    const __bf16* vb = vT + ((long)(b * HH + h) * TT << 6);
    const float*  Fb = F  + (long)b * TT * TT;
    __bf16* Pl = &Pls[w][0];

    f32x4 O[4] = {};
    float mr[4], lr[4];
#pragma unroll
    for (int r = 0; r < 4; r++) { mr[r] = -1e30f; lr[r] = 0.0f; }

    for (int jt = 0; jt <= jmax; jt += 32) {
        const bool masked = (jt + 31 > i0);
        float sc[2][4];
#pragma unroll
        for (int jh = 0; jh < 2; jh++) {
            const __bf16* kp = kb + (((long)(jt + jh * 16 + l16)) << 6) + quad * 8;
            bf16x8 b0 = *(const bf16x8*)kp, b1 = *(const bf16x8*)(kp + 32);
            f32x4 acc = {};
            acc = mfma16(aq0, b0, acc);
            acc = mfma16(aq1, b1, acc);
            const int j = jt + jh * 16 + l16;
#pragma unroll
            for (int r = 0; r < 4; r++) {
                const int i = i0 + quad * 4 + r;
                float v = fmaf(acc[r], 0.125f, -Fb[(long)i * TT + j]);
                if (masked) v = (j <= i) ? v : -1e30f;
                sc[jh][r] = v;
            }
        }
        // online softmax (row stats live in the 16 lanes of each quad-group)
        float al[4];
#pragma unroll
        for (int r = 0; r < 4; r++) {
            float t = fmaxf(sc[0][r], sc[1][r]);
#pragma unroll
            for (int off = 8; off >= 1; off >>= 1) t = fmaxf(t, __shfl_xor(t, off, 16));
            const float mn = fmaxf(mr[r], t);
            al[r] = __expf(mr[r] - mn);
            mr[r] = mn;
            float p0 = __expf(sc[0][r] - mn);
            float p1 = __expf(sc[1][r] - mn);
            sc[0][r] = p0; sc[1][r] = p1;
            float su = p0 + p1;
#pragma unroll
            for (int off = 8; off >= 1; off >>= 1) su += __shfl_xor(su, off, 16);
            lr[r] = lr[r] * al[r] + su;
        }
#pragma unroll
        for (int db = 0; db < 4; db++) {
            O[db][0] *= al[0]; O[db][1] *= al[1]; O[db][2] *= al[2]; O[db][3] *= al[3];
        }
        // P -> LDS (C-layout -> row-major [i][j]), wave-private, no barrier needed
#pragma unroll
        for (int r = 0; r < 4; r++) {
            const int il = quad * 4 + r;
            Pl[il * 40 + l16]      = (__bf16)sc[0][r];
            Pl[il * 40 + 16 + l16] = (__bf16)sc[1][r];
        }
        const bf16x8 ap = *(const bf16x8*)(Pl + l16 * 40 + quad * 8);
#pragma unroll
        for (int db = 0; db < 4; db++) {
            const bf16x8 bv = *(const bf16x8*)(vb + ((long)(db * 16 + l16) * TT) + jt + quad * 8);
            O[db] = mfma16(ap, bv, O[db]);
        }
    }

    float inv[4];
#pragma unroll
    for (int r = 0; r < 4; r++) inv[r] = 1.0f / lr[r];
#pragma unroll
    for (int db = 0; db < 4; db++) {
#pragma unroll
        for (int r = 0; r < 4; r++) {
            const int i = i0 + quad * 4 + r;
            y[((long)(b * TT + i)) * (HH * DD) + h * 64 + db * 16 + l16] = (__bf16)(O[db][r] * inv[r]);
        }
    }
}

// ---------------------------------------------------------------------------
extern "C" void kernel_launch(void* const* d_in, const int* in_sizes, int n_in,
                              void* d_out, int out_size, void* d_ws, size_t ws_size,
                              hipStream_t stream)
{
    const float* x      = (const float*)d_in[0];
    const float* w_attn = (const float*)d_in[1];
    const float* b_attn = (const float*)d_in[2];
    const float* w_proj = (const float*)d_in[3];
    const float* b_proj = (const float*)d_in[4];
    float* out = (float*)d_out;

    char* ws = (char*)d_ws;
    __bf16* xb  = (__bf16*)ws; ws += (long)MTOT * CC * 2;          // 6,291,456
    __bf16* wab = (__bf16*)ws; ws += (long)NQKV * CC * 2;          // 3,538,944
    __bf16* wpb = (__bf16*)ws; ws += (long)CC * (HH*DD) * 2;       // 1,179,648
    __bf16* qb  = (__bf16*)ws; ws += (long)BB * HH * TT * DD * 2;  // 6,291,456
    __bf16* kb  = (__bf16*)ws; ws += (long)BB * HH * TT * DD * 2;
    __bf16* vtb = (__bf16*)ws; ws += (long)BB * HH * TT * DD * 2;
    float*  SF  = (float*)ws;  ws += (long)BB * TT * TT * 4;       // 33,554,432
    float*  cs  = (float*)ws;  ws += (long)BB * 16 * TT * 4;       // 262,144
    __bf16* yb  = (__bf16*)ws; ws += (long)MTOT * (HH*DD) * 2;     // 6,291,456

    // 1) convert inputs to bf16
    cvt_bf16_kernel<<<5376, 256, 0, stream>>>(x, w_attn, w_proj, xb, wab, wpb);
    // 2) QKV projection -> q, k, vT (bf16)
    gemm_nt_kernel<0><<<dim3(NQKV / 128, MTOT / 128), 256, 0, stream>>>(
        xb, wab, b_attn, qb, kb, vtb, nullptr, CC);
    // 3) head-0 selection scores S
    sgemm_kernel<<<dim3(TT / 64, TT / 64, BB), 256, 0, stream>>>(qb, kb, SF);
    // 4) exclusive cumsum over query dim -> F (in place)
    scan_sum_kernel<<<dim3(TT / 256, 16, BB), 256, 0, stream>>>(SF, cs);
    scan_write_kernel<<<dim3(TT / 256, 16, BB), 256, 0, stream>>>(SF, cs);
    // 5) flash attention with F subtraction -> y (bf16)
    flash_kernel<<<dim3(TT / 64, HH, BB), 256, 0, stream>>>(qb, kb, vtb, SF, yb);
    // 6) output projection -> out (f32)
    gemm_nt_kernel<1><<<dim3((HH*DD) / 128, MTOT / 128), 256, 0, stream>>>(
        yb, wpb, b_proj, nullptr, nullptr, nullptr, out, HH * DD);
}

// Round 2
// 282.650 us; speedup vs baseline: 1.2683x; 1.2683x over previous
//
#include <hip/hip_runtime.h>
#include <hip/hip_bf16.h>

// Problem constants
#define BB 2
#define TT 2048
#define CC 768
#define HH 12
#define DD 64
#define NQKV 2304           // 3*H*D
#define MTOT (BB*TT)        // 4096

typedef __bf16 bf16x8 __attribute__((ext_vector_type(8)));
typedef __bf16 bf16x4 __attribute__((ext_vector_type(4)));
typedef float  f32x4  __attribute__((ext_vector_type(4)));

__device__ __forceinline__ f32x4 mfma16(bf16x8 a, bf16x8 b, f32x4 c) {
    return __builtin_amdgcn_mfma_f32_16x16x32_bf16(a, b, c, 0, 0, 0);
}

// ---------------------------------------------------------------------------
// 1) f32 -> bf16 convert for x, w_attn, w_proj (one fused elementwise kernel)
// ---------------------------------------------------------------------------
__global__ __launch_bounds__(256) void cvt_bf16_kernel(
    const float* __restrict__ x, const float* __restrict__ wa, const float* __restrict__ wp,
    __bf16* __restrict__ xb, __bf16* __restrict__ wab, __bf16* __restrict__ wpb)
{
    const long NX = (long)MTOT * CC;       // 3,145,728
    const long NWA = (long)NQKV * CC;      // 1,769,472
    long idx = ((long)blockIdx.x * 256 + threadIdx.x) * 4;
    const float* src; __bf16* dst; long off;
    if (idx < NX)            { src = x;  dst = xb;  off = idx; }
    else if (idx < NX + NWA) { src = wa; dst = wab; off = idx - NX; }
    else                     { src = wp; dst = wpb; off = idx - NX - NWA; }
    float4 v = *(const float4*)(src + off);
    bf16x4 o;
    o[0] = (__bf16)v.x; o[1] = (__bf16)v.y; o[2] = (__bf16)v.z; o[3] = (__bf16)v.w;
    *(bf16x4*)(dst + off) = o;
}

// ---------------------------------------------------------------------------
// 2) NT GEMM (A[M,K] row-major, B[N,K] row-major), 128x128 tile, BK=32,
//    bf16 MFMA 16x16x32. EPI=0: QKV epilogue (scatter to q,k,vT bf16).
//    EPI=1: proj epilogue (f32 out).
// ---------------------------------------------------------------------------
template<int EPI>
__global__ __launch_bounds__(256, 2) void gemm_nt_kernel(
    const __bf16* __restrict__ A, const __bf16* __restrict__ Bw,
    const float* __restrict__ bias,
    __bf16* __restrict__ oQ, __bf16* __restrict__ oK, __bf16* __restrict__ oVT,
    float* __restrict__ oOut, int K)
{
    __shared__ __align__(16) __bf16 As[128 * 32];
    __shared__ __align__(16) __bf16 Bs[128 * 32];
    const int tid = threadIdx.x;
    const int m0 = blockIdx.y * 128, n0 = blockIdx.x * 128;
    const int w = tid >> 6, lane = tid & 63, quad = lane >> 4, l16 = lane & 15;
    const int wm = (w >> 1) * 64, wn = (w & 1) * 64;
    const int sr = tid >> 2, scc = (tid & 3) * 8;   // staging row / col

    f32x4 acc[4][4] = {};

    for (int kt = 0; kt < K; kt += 32) {
        __syncthreads();
        *(uint4*)(As + sr * 32 + scc)        = *(const uint4*)(A  + (long)(m0 + sr) * K      + kt + scc);
        *(uint4*)(As + (sr + 64) * 32 + scc) = *(const uint4*)(A  + (long)(m0 + sr + 64) * K + kt + scc);
        *(uint4*)(Bs + sr * 32 + scc)        = *(const uint4*)(Bw + (long)(n0 + sr) * K      + kt + scc);
        *(uint4*)(Bs + (sr + 64) * 32 + scc) = *(const uint4*)(Bw + (long)(n0 + sr + 64) * K + kt + scc);
        __syncthreads();

        bf16x8 af[4], bfr[4];
#pragma unroll
        for (int g = 0; g < 4; g++)  af[g]  = *(const bf16x8*)(As + (wm + g * 16 + l16) * 32 + quad * 8);
#pragma unroll
        for (int jb = 0; jb < 4; jb++) bfr[jb] = *(const bf16x8*)(Bs + (wn + jb * 16 + l16) * 32 + quad * 8);
#pragma unroll
        for (int g = 0; g < 4; g++)
#pragma unroll
            for (int jb = 0; jb < 4; jb++)
                acc[g][jb] = mfma16(af[g], bfr[jb], acc[g][jb]);
    }

    // epilogue: C/D layout col = lane&15, row = quad*4 + reg
#pragma unroll
    for (int jb = 0; jb < 4; jb++) {
        const int n = n0 + wn + jb * 16 + l16;
        const float bv = bias[n];
#pragma unroll
        for (int g = 0; g < 4; g++) {
#pragma unroll
            for (int r = 0; r < 4; r++) {
                const int m = m0 + wm + g * 16 + quad * 4 + r;
                const float v = acc[g][jb][r] + bv;
                if (EPI == 0) {
                    const int which = n / 768;
                    const int rem = n - which * 768;
                    const int h = rem >> 6, d = rem & 63;
                    const int b = m >> 11, t = m & 2047;
                    const __bf16 hv = (__bf16)v;
                    if (which == 0)      oQ [(((b * HH + h) * TT + t) << 6) + d] = hv;
                    else if (which == 1) oK [(((b * HH + h) * TT + t) << 6) + d] = hv;
                    else                 oVT[((((b * HH + h) << 6) + d) * TT) + t] = hv;
                } else {
                    oOut[(long)m * CC + n] = v;
                }
            }
        }
    }
}

// ---------------------------------------------------------------------------
// 3) Head-0 selection scores: S[b,i,j] = (1<=j<i) ? relu(q0_i . k0_j * 0.125) : 0
// ---------------------------------------------------------------------------
__global__ __launch_bounds__(256) void sgemm_kernel(
    const __bf16* __restrict__ q, const __bf16* __restrict__ k, float* __restrict__ S)
{
    const int tj = blockIdx.x, ti = blockIdx.y, b = blockIdx.z;
    if (tj > ti) return;
    const int w = threadIdx.x >> 6, lane = threadIdx.x & 63, quad = lane >> 4, l16 = lane & 15;
    const int i0 = ti * 64 + w * 16;

    const __bf16* qp = q + (((long)(b * HH + 0) * TT + i0 + l16) << 6) + quad * 8;
    bf16x8 a0 = *(const bf16x8*)qp, a1 = *(const bf16x8*)(qp + 32);
    const __bf16* kbase = k + ((long)(b * HH + 0) * TT << 6);

#pragma unroll
    for (int jb = 0; jb < 4; jb++) {
        const __bf16* kp = kbase + (((long)(tj * 64 + jb * 16 + l16)) << 6) + quad * 8;
        bf16x8 b0 = *(const bf16x8*)kp, b1 = *(const bf16x8*)(kp + 32);
        f32x4 acc = {};
        acc = mfma16(a0, b0, acc);
        acc = mfma16(a1, b1, acc);
        const int j = tj * 64 + jb * 16 + l16;
#pragma unroll
        for (int r = 0; r < 4; r++) {
            const int i = i0 + quad * 4 + r;
            float v = fmaxf(acc[r] * 0.125f, 0.0f);
            v = (j >= 1 && j < i) ? v : 0.0f;
            S[((long)b * TT + i) * TT + j] = v;
        }
    }
}

// ---------------------------------------------------------------------------
// 4) Exclusive cumsum over query dim (axis i), per column j: 2-pass chunked.
// ---------------------------------------------------------------------------
__global__ __launch_bounds__(256) void scan_sum_kernel(
    const float* __restrict__ S, float* __restrict__ csum)
{
    const int j = blockIdx.x * 256 + threadIdx.x;
    const int chunk = blockIdx.y, b = blockIdx.z;
    const int ib = chunk * 128;
    const float* p = S + ((long)b * TT + ib) * TT + j;
    float s = 0.0f;
#pragma unroll 4
    for (int ii = 0; ii < 128; ii++) {
        float v = p[(long)ii * TT];
        s += ((ib + ii) > j) ? v : 0.0f;
    }
    csum[(b * 16 + chunk) * TT + j] = s;
}

__global__ __launch_bounds__(256) void scan_write_kernel(
    float* __restrict__ S, const float* __restrict__ csum)
{
    const int j = blockIdx.x * 256 + threadIdx.x;
    const int chunk = blockIdx.y, b = blockIdx.z;
    const int ib = chunk * 128;
    float off = 0.0f;
    for (int c = 0; c < chunk; c++) off += csum[(b * 16 + c) * TT + j];
    float* p = S + ((long)b * TT + ib) * TT + j;
#pragma unroll 4
    for (int ii = 0; ii < 128; ii++) {
        float v = p[(long)ii * TT];
        v = ((ib + ii) > j) ? v : 0.0f;
        p[(long)ii * TT] = off;    // exclusive: write before add
        off += v;
    }
}

// ---------------------------------------------------------------------------
// 5) Flash attention with F subtraction. v2:
//    - 4 waves/block, each wave owns ONE 16-row q-tile; the 4 tiles are
//      {bid, 63-bid, 64+bid, 127-bid} -> per-block work is CONSTANT
//      (258 q-rows) -> no causal tail imbalance.
//    - K-tile widened 32 -> 64 (half the softmax shuffle chains per key).
//    - register software pipeline: next K-tile + current V-tile loads are
//      issued before the F/softmax phase so global latency overlaps VALU.
// ---------------------------------------------------------------------------
__global__ __launch_bounds__(256, 3) void flash_kernel(
    const __bf16* __restrict__ q, const __bf16* __restrict__ k, const __bf16* __restrict__ vT,
    const float* __restrict__ F, __bf16* __restrict__ y)
{
    __shared__ __align__(16) __bf16 Pls[4][16 * 72];   // per-wave 16x64 P tile, stride 72
    const int bid = blockIdx.x, h = blockIdx.y, b = blockIdx.z;
    const int w = threadIdx.x >> 6, lane = threadIdx.x & 63, quad = lane >> 4, l16 = lane & 15;
    int qt;
    if      (w == 0) qt = bid;
    else if (w == 1) qt = 63 - bid;
    else if (w == 2) qt = 64 + bid;
    else             qt = 127 - bid;
    const int i0 = qt * 16;
    const int jmax = i0 + 15;

    const __bf16* qp = q + (((long)(b * HH + h) * TT + i0 + l16) << 6) + quad * 8;
    const bf16x8 aq0 = *(const bf16x8*)qp;
    const bf16x8 aq1 = *(const bf16x8*)(qp + 32);
    const __bf16* kb = k  + ((long)(b * HH + h) * TT << 6);
    const __bf16* vb = vT + ((long)(b * HH + h) * TT << 6);
    const float*  Fb = F  + (long)b * TT * TT;
    __bf16* Pl = &Pls[w][0];

    f32x4 O[4] = {};
    float mr[4], lr[4];
#pragma unroll
    for (int r = 0; r < 4; r++) { mr[r] = -1e30f; lr[r] = 0.0f; }

    // prefetch K-tile 0 (4 jh groups x 2 frags)
    bf16x8 kc0[4], kc1[4];
#pragma unroll
    for (int jh = 0; jh < 4; jh++) {
        const __bf16* kp = kb + (((long)(jh * 16 + l16)) << 6) + quad * 8;
        kc0[jh] = *(const bf16x8*)kp;
        kc1[jh] = *(const bf16x8*)(kp + 32);
    }

    for (int jt = 0; jt <= jmax; jt += 64) {
        // ---- QK MFMAs on the prefetched K tile ----
        float sc[4][4];
#pragma unroll
        for (int jh = 0; jh < 4; jh++) {
            f32x4 acc = {};
            acc = mfma16(aq0, kc0[jh], acc);
            acc = mfma16(aq1, kc1[jh], acc);
#pragma unroll
            for (int r = 0; r < 4; r++) sc[jh][r] = acc[r];
        }
        // ---- prefetch next K tile (overlaps softmax below) ----
        const int jt2 = jt + 64;
        if (jt2 <= jmax) {
#pragma unroll
            for (int jh = 0; jh < 4; jh++) {
                const __bf16* kp = kb + (((long)(jt2 + jh * 16 + l16)) << 6) + quad * 8;
                kc0[jh] = *(const bf16x8*)kp;
                kc1[jh] = *(const bf16x8*)(kp + 32);
            }
        }
        // ---- prefetch current V tile (used after softmax) ----
        bf16x8 vv0[4], vv1[4];
#pragma unroll
        for (int db = 0; db < 4; db++) {
            const __bf16* vp = vb + ((long)(db * 16 + l16) * TT) + jt + quad * 8;
            vv0[db] = *(const bf16x8*)vp;
            vv1[db] = *(const bf16x8*)(vp + 32);
        }
        // ---- F subtraction + causal mask ----
        const bool masked = (jt + 63 > i0);
#pragma unroll
        for (int jh = 0; jh < 4; jh++) {
            const int j = jt + jh * 16 + l16;
#pragma unroll
            for (int r = 0; r < 4; r++) {
                const int i = i0 + quad * 4 + r;
                float v = fmaf(sc[jh][r], 0.125f, -Fb[(long)i * TT + j]);
                if (masked) v = (j <= i) ? v : -1e30f;
                sc[jh][r] = v;
            }
        }
        // ---- online softmax (row stats across the 16 lanes of each quad) ----
        float al[4];
#pragma unroll
        for (int r = 0; r < 4; r++) {
            float t = fmaxf(fmaxf(sc[0][r], sc[1][r]), fmaxf(sc[2][r], sc[3][r]));
#pragma unroll
            for (int off = 8; off >= 1; off >>= 1) t = fmaxf(t, __shfl_xor(t, off, 16));
            const float mn = fmaxf(mr[r], t);
            al[r] = __expf(mr[r] - mn);
            mr[r] = mn;
            float su = 0.0f;
#pragma unroll
            for (int jh = 0; jh < 4; jh++) {
                const float p = __expf(sc[jh][r] - mn);
                sc[jh][r] = p;
                su += p;
            }
#pragma unroll
            for (int off = 8; off >= 1; off >>= 1) su += __shfl_xor(su, off, 16);
            lr[r] = lr[r] * al[r] + su;
        }
#pragma unroll
        for (int db = 0; db < 4; db++) {
            O[db][0] *= al[0]; O[db][1] *= al[1]; O[db][2] *= al[2]; O[db][3] *= al[3];
        }
        // ---- P -> LDS (C-layout -> row-major [i][j]), wave-private ----
#pragma unroll
        for (int r = 0; r < 4; r++) {
            const int il = quad * 4 + r;
#pragma unroll
            for (int jh = 0; jh < 4; jh++)
                Pl[il * 72 + jh * 16 + l16] = (__bf16)sc[jh][r];
        }
        const bf16x8 ap0 = *(const bf16x8*)(Pl + l16 * 72 + quad * 8);
        const bf16x8 ap1 = *(const bf16x8*)(Pl + l16 * 72 + 32 + quad * 8);
        // ---- PV ----
#pragma unroll
        for (int db = 0; db < 4; db++) {
            O[db] = mfma16(ap0, vv0[db], O[db]);
            O[db] = mfma16(ap1, vv1[db], O[db]);
        }
    }

    float inv[4];
#pragma unroll
    for (int r = 0; r < 4; r++) inv[r] = 1.0f / lr[r];
#pragma unroll
    for (int db = 0; db < 4; db++) {
#pragma unroll
        for (int r = 0; r < 4; r++) {
            const int i = i0 + quad * 4 + r;
            y[((long)(b * TT + i)) * (HH * DD) + h * 64 + db * 16 + l16] = (__bf16)(O[db][r] * inv[r]);
        }
    }
}

// ---------------------------------------------------------------------------
extern "C" void kernel_launch(void* const* d_in, const int* in_sizes, int n_in,
                              void* d_out, int out_size, void* d_ws, size_t ws_size,
                              hipStream_t stream)
{
    const float* x      = (const float*)d_in[0];
    const float* w_attn = (const float*)d_in[1];
    const float* b_attn = (const float*)d_in[2];
    const float* w_proj = (const float*)d_in[3];
    const float* b_proj = (const float*)d_in[4];
    float* out = (float*)d_out;

    char* ws = (char*)d_ws;
    __bf16* xb  = (__bf16*)ws; ws += (long)MTOT * CC * 2;          // 6,291,456
    __bf16* wab = (__bf16*)ws; ws += (long)NQKV * CC * 2;          // 3,538,944
    __bf16* wpb = (__bf16*)ws; ws += (long)CC * (HH*DD) * 2;       // 1,179,648
    __bf16* qb  = (__bf16*)ws; ws += (long)BB * HH * TT * DD * 2;  // 6,291,456
    __bf16* kb  = (__bf16*)ws; ws += (long)BB * HH * TT * DD * 2;
    __bf16* vtb = (__bf16*)ws; ws += (long)BB * HH * TT * DD * 2;
    float*  SF  = (float*)ws;  ws += (long)BB * TT * TT * 4;       // 33,554,432
    float*  cs  = (float*)ws;  ws += (long)BB * 16 * TT * 4;       // 262,144
    __bf16* yb  = (__bf16*)ws; ws += (long)MTOT * (HH*DD) * 2;     // 6,291,456

    // 1) convert inputs to bf16
    cvt_bf16_kernel<<<5376, 256, 0, stream>>>(x, w_attn, w_proj, xb, wab, wpb);
    // 2) QKV projection -> q, k, vT (bf16)
    gemm_nt_kernel<0><<<dim3(NQKV / 128, MTOT / 128), 256, 0, stream>>>(
        xb, wab, b_attn, qb, kb, vtb, nullptr, CC);
    // 3) head-0 selection scores S
    sgemm_kernel<<<dim3(TT / 64, TT / 64, BB), 256, 0, stream>>>(qb, kb, SF);
    // 4) exclusive cumsum over query dim -> F (in place)
    scan_sum_kernel<<<dim3(TT / 256, 16, BB), 256, 0, stream>>>(SF, cs);
    scan_write_kernel<<<dim3(TT / 256, 16, BB), 256, 0, stream>>>(SF, cs);
    // 5) flash attention with F subtraction -> y (bf16)
    flash_kernel<<<dim3(32, HH, BB), 256, 0, stream>>>(qb, kb, vtb, SF, yb);
    // 6) output projection -> out (f32)
    gemm_nt_kernel<1><<<dim3((HH*DD) / 128, MTOT / 128), 256, 0, stream>>>(
        yb, wpb, b_proj, nullptr, nullptr, nullptr, out, HH * DD);
}